// Round 4
// baseline (461.443 us; speedup 1.0000x reference)
//
#include <hip/hip_runtime.h>
#include <math.h>

#define IMG_H 512
#define IMG_W 512
#define KW 11
#define RAD 5
#define T 4                     // output rows per thread
#define NROWS (T + 2 * RAD)     // 14 input rows walked
#define NG (IMG_W / 4)          // 128 float4 column-groups per row

#define C1F (0.01f * 0.01f)
#define C2F (0.03f * 0.03f)

__device__ __forceinline__ float ssim_px(float mu1, float mu2, float sp) {
    float m12 = mu1 * mu2;
    float sigma = sp - m12;
    float sq = mu1 * mu1 + mu2 * mu2;
    return ((2.f * m12 + C1F) * (2.f * sigma + C2F)) / ((sq + C1F) * (sq + C2F));
}

// Each thread: 4 cols (one float4 group) x 4 output rows, in registers.
// Block: 256 threads = 128 col-groups x 2 row-chunks -> 512 wide x 8 rows.
// Grid: (64 row-blocks, 32 images) = 2048 blocks.
//
// Round-1 lesson: (256,5) forces VGPR<=64 -> scratch spill catastrophe.
// Round-2 result: 64 VGPR / 8 waves, VALUBusy=48%, 80 us -> latency-bound on
//   the serial per-row load->h-conv dependency (VALUBusy scales with waves).
// Round-3 lesson: double-buffer as bA[2][3] with parity indices -> compiler
//   left the arrays runtime-indexed -> scratch (rule #20), 839 MB writes.
// This round: same 1-deep row prefetch but with NAMED float4 buffers and the
// 14-row loop instantiated by macro with compile-time literals everywhere.
// Budget ~123 VGPR -> 4 waves/SIMD under launch_bounds(256,4); each wave has
// a full iteration (~1600 wall cycles at 4 waves) between prefetch issue and
// first use -> covers L2/L3 latency.
__global__ __launch_bounds__(256, 4)
void ssim_fused_kernel(const float* __restrict__ A, const float* __restrict__ B,
                       float* __restrict__ out, float inv_total) {
    __shared__ float wpart[4];

    const int tid = threadIdx.x;
    const int g = tid & (NG - 1);        // col-group 0..127
    const int rchunk = tid >> 7;         // 0..1 (wave-uniform)
    const int img = blockIdx.y;
    const int ybase = blockIdx.x * (2 * T) + rchunk * T;   // first output row

    // Gaussian weights (sigma=1.5, K=11) — fp32 recipe matching np bit-exactly.
    float w[KW];
    {
        float s = 0.f;
#pragma unroll
        for (int i = 0; i < KW; ++i) {
            float d = (float)(i - RAD);
            w[i] = expf(-(d * d) / 4.5f);
            s += w[i];
        }
        float inv = 1.0f / s;
#pragma unroll
        for (int i = 0; i < KW; ++i) {
            w[i] *= inv;
            w[i] = __int_as_float(__builtin_amdgcn_readfirstlane(__float_as_int(w[i])));
        }
    }

    const float* __restrict__ Ai = A + (size_t)img * IMG_H * IMG_W;
    const float* __restrict__ Bi = B + (size_t)img * IMG_H * IMG_W;

    float4 accA[T], accB[T], accP[T];
#pragma unroll
    for (int o = 0; o < T; ++o) {
        accA[o] = make_float4(0.f, 0.f, 0.f, 0.f);
        accB[o] = accA[o];
        accP[o] = accA[o];
    }

    // Double-buffered row registers as NAMED variables (never runtime-indexed).
    // Zero-init once: lane g==0 never writes *A0/*B0, lane g==127 never writes
    // *A2/*B2 — the zeros ARE the conv zero-padding for those lanes.
    const float4 z4 = make_float4(0.f, 0.f, 0.f, 0.f);
    float4 eA0 = z4, eA1 = z4, eA2 = z4, eB0 = z4, eB1 = z4, eB2 = z4;
    float4 oA0 = z4, oA1 = z4, oA2 = z4, oB0 = z4, oB1 = z4, oB2 = z4;

// Load row GY into slot P (halo guards are per-lane; masked lanes keep zeros).
#define PRE(P, GY)                                                        \
    {                                                                     \
        int gy2_ = (GY);                                                  \
        if (gy2_ >= 0 && gy2_ < IMG_H) {                                  \
            const float* rA_ = Ai + (size_t)gy2_ * IMG_W;                 \
            const float* rB_ = Bi + (size_t)gy2_ * IMG_W;                 \
            if (g >= 1) {                                                 \
                P##A0 = *(const float4*)(rA_ + 4 * (g - 1));              \
                P##B0 = *(const float4*)(rB_ + 4 * (g - 1));              \
            }                                                             \
            P##A1 = *(const float4*)(rA_ + 4 * g);                        \
            P##B1 = *(const float4*)(rB_ + 4 * g);                        \
            if (g <= NG - 2) {                                            \
                P##A2 = *(const float4*)(rA_ + 4 * (g + 1));              \
                P##B2 = *(const float4*)(rB_ + 4 * (g + 1));              \
            }                                                             \
        }                                                                 \
    }

// One horizontal tap-source j: contributes to cols c with k=j-c in [0,11).
// Per-c accumulation order is k-ascending when HJ(0..13) run in order ==
// bit-identical to the verified round-2 k-loop.
#define HJ(J)                                                             \
    {                                                                     \
        float t_ = fa[J] * fb[J];                                         \
        _Pragma("unroll")                                                 \
        for (int c_ = 0; c_ < 4; ++c_) {                                  \
            int k_ = (J) - c_;                                            \
            if (k_ >= 0 && k_ < KW) {                                     \
                hA[c_] += w[k_] * fa[J];                                  \
                hB[c_] += w[k_] * fb[J];                                  \
                hP[c_] += w[k_] * t_;                                     \
            }                                                             \
        }                                                                 \
    }

// Consume slot P as input row I (gy = ybase+I-RAD): h-conv + vertical scatter.
#define CONS(I, P)                                                        \
    {                                                                     \
        int gy_ = ybase + (I) - RAD;                                      \
        if (gy_ >= 0 && gy_ < IMG_H) {                                    \
            const float* rA_ = Ai + (size_t)gy_ * IMG_W;                  \
            const float* rB_ = Bi + (size_t)gy_ * IMG_W;                  \
            int cl_ = 4 * g - 5, cr_ = 4 * g + 8;                         \
            float ea0_ = (cl_ >= 0) ? rA_[cl_] : 0.f;                     \
            float eb0_ = (cl_ >= 0) ? rB_[cl_] : 0.f;                     \
            float ea1_ = (cr_ < IMG_W) ? rA_[cr_] : 0.f;                  \
            float eb1_ = (cr_ < IMG_W) ? rB_[cr_] : 0.f;                  \
            float fa[14] = {ea0_, P##A0.x, P##A0.y, P##A0.z, P##A0.w,     \
                            P##A1.x, P##A1.y, P##A1.z, P##A1.w,           \
                            P##A2.x, P##A2.y, P##A2.z, P##A2.w, ea1_};    \
            float fb[14] = {eb0_, P##B0.x, P##B0.y, P##B0.z, P##B0.w,     \
                            P##B1.x, P##B1.y, P##B1.z, P##B1.w,           \
                            P##B2.x, P##B2.y, P##B2.z, P##B2.w, eb1_};    \
            float hA[4] = {0.f, 0.f, 0.f, 0.f};                           \
            float hB[4] = {0.f, 0.f, 0.f, 0.f};                           \
            float hP[4] = {0.f, 0.f, 0.f, 0.f};                           \
            HJ(0) HJ(1) HJ(2) HJ(3) HJ(4) HJ(5) HJ(6)                     \
            HJ(7) HJ(8) HJ(9) HJ(10) HJ(11) HJ(12) HJ(13)                 \
            _Pragma("unroll")                                             \
            for (int o_ = 0; o_ < T; ++o_) {                              \
                int k_ = (I) - o_;                                        \
                if (k_ >= 0 && k_ < KW) {                                 \
                    float wk_ = w[k_];                                    \
                    accA[o_].x += wk_ * hA[0]; accA[o_].y += wk_ * hA[1]; \
                    accA[o_].z += wk_ * hA[2]; accA[o_].w += wk_ * hA[3]; \
                    accB[o_].x += wk_ * hB[0]; accB[o_].y += wk_ * hB[1]; \
                    accB[o_].z += wk_ * hB[2]; accB[o_].w += wk_ * hB[3]; \
                    accP[o_].x += wk_ * hP[0]; accP[o_].y += wk_ * hP[1]; \
                    accP[o_].z += wk_ * hP[2]; accP[o_].w += wk_ * hP[3]; \
                }                                                         \
            }                                                             \
        }                                                                 \
    }

// Step I: issue row I+1's loads into slot NP, then consume slot CP as row I.
#define STEP(I, CP, NP)                                                   \
    {                                                                     \
        if ((I) + 1 < NROWS) PRE(NP, ybase + (I) + 1 - RAD)               \
        CONS(I, CP)                                                       \
    }

    // Prologue: row 0 into the even slot.
    PRE(e, ybase - RAD)

    STEP(0, e, o)
    STEP(1, o, e)
    STEP(2, e, o)
    STEP(3, o, e)
    STEP(4, e, o)
    STEP(5, o, e)
    STEP(6, e, o)
    STEP(7, o, e)
    STEP(8, e, o)
    STEP(9, o, e)
    STEP(10, e, o)
    STEP(11, o, e)
    STEP(12, e, o)
    STEP(13, o, e)

#undef STEP
#undef CONS
#undef HJ
#undef PRE

    // SSIM formula per pixel + per-thread accumulate (16 px/thread).
    float acc = 0.f;
#pragma unroll
    for (int o = 0; o < T; ++o) {
        acc += ssim_px(accA[o].x, accB[o].x, accP[o].x);
        acc += ssim_px(accA[o].y, accB[o].y, accP[o].y);
        acc += ssim_px(accA[o].z, accB[o].z, accP[o].z);
        acc += ssim_px(accA[o].w, accB[o].w, accP[o].w);
    }

    // Reduce: wave shuffle -> LDS -> one atomic per block.
#pragma unroll
    for (int off = 32; off > 0; off >>= 1)
        acc += __shfl_down(acc, off, 64);
    int wid = tid >> 6;
    int lane = tid & 63;
    if (lane == 0) wpart[wid] = acc;
    __syncthreads();
    if (tid == 0) {
        float s = (wpart[0] + wpart[1]) + (wpart[2] + wpart[3]);
        atomicAdd(out, s * inv_total);
    }
}

extern "C" void kernel_launch(void* const* d_in, const int* in_sizes, int n_in,
                              void* d_out, int out_size, void* d_ws, size_t ws_size,
                              hipStream_t stream) {
    const float* A = (const float*)d_in[0];
    const float* B = (const float*)d_in[1];
    float* out = (float*)d_out;

    const int total = in_sizes[0];                 // 32*1*512*512
    const int nimg = total / (IMG_H * IMG_W);      // 32

    hipMemsetAsync(d_out, 0, sizeof(float), stream);

    dim3 grid(IMG_H / (2 * T), nimg, 1);           // (64, 32)
    ssim_fused_kernel<<<grid, 256, 0, stream>>>(A, B, out, 1.0f / (float)total);
}

// Round 5
// 172.613 us; speedup vs baseline: 2.6733x; 2.6733x over previous
//
#include <hip/hip_runtime.h>
#include <math.h>

#define IMG_H 512
#define IMG_W 512
#define KW 11
#define RAD 5
#define T 4                     // output rows per thread
#define NROWS (T + 2 * RAD)     // 14 input rows walked
#define NG (IMG_W / 4)          // 128 float4 column-groups per row

#define C1F (0.01f * 0.01f)
#define C2F (0.03f * 0.03f)

__device__ __forceinline__ float ssim_px(float mu1, float mu2, float sp) {
    float m12 = mu1 * mu2;
    float sigma = sp - m12;
    float sq = mu1 * mu1 + mu2 * mu2;
    return ((2.f * m12 + C1F) * (2.f * sigma + C2F)) / ((sq + C1F) * (sq + C2F));
}

// Each thread: 4 cols (one float4 group) x 4 output rows, in registers.
// Block: 256 threads = 128 col-groups x 2 row-chunks -> 512 wide x 8 rows.
// Grid: (64 row-blocks, 32 images) = 2048 blocks.
//
// ALLOCATOR LAW (measured rounds 0-4): VGPR cap ~= 256 / min_waves_per_EU.
//   (256,2) -> cap 128 (round 0: honest 92, no spill)
//   (256,4) -> cap 64  (rounds 2/3/4: spills whenever demand > 64)
//   (256,5) -> cap 48  (round 1: catastrophe)
// The 1-deep row-prefetch below needs ~120 VGPR -> must use (256,2).
// Named float4 double-buffers + macro-unrolled 14-row walk (rule #20: no
// runtime-indexed arrays anywhere).
__global__ __launch_bounds__(256, 2)
void ssim_fused_kernel(const float* __restrict__ A, const float* __restrict__ B,
                       float* __restrict__ out, float inv_total) {
    __shared__ float wpart[4];

    const int tid = threadIdx.x;
    const int g = tid & (NG - 1);        // col-group 0..127
    const int rchunk = tid >> 7;         // 0..1 (wave-uniform)
    const int img = blockIdx.y;
    const int ybase = blockIdx.x * (2 * T) + rchunk * T;   // first output row

    // Gaussian weights (sigma=1.5, K=11) — fp32 recipe matching np bit-exactly.
    float w[KW];
    {
        float s = 0.f;
#pragma unroll
        for (int i = 0; i < KW; ++i) {
            float d = (float)(i - RAD);
            w[i] = expf(-(d * d) / 4.5f);
            s += w[i];
        }
        float inv = 1.0f / s;
#pragma unroll
        for (int i = 0; i < KW; ++i) {
            w[i] *= inv;
            w[i] = __int_as_float(__builtin_amdgcn_readfirstlane(__float_as_int(w[i])));
        }
    }

    const float* __restrict__ Ai = A + (size_t)img * IMG_H * IMG_W;
    const float* __restrict__ Bi = B + (size_t)img * IMG_H * IMG_W;

    float4 accA[T], accB[T], accP[T];
#pragma unroll
    for (int o = 0; o < T; ++o) {
        accA[o] = make_float4(0.f, 0.f, 0.f, 0.f);
        accB[o] = accA[o];
        accP[o] = accA[o];
    }

    // Double-buffered row registers as NAMED variables (never runtime-indexed).
    // Zero-init once: lane g==0 never writes *A0/*B0, lane g==127 never writes
    // *A2/*B2 — the zeros ARE the conv zero-padding for those lanes.
    const float4 z4 = make_float4(0.f, 0.f, 0.f, 0.f);
    float4 eA0 = z4, eA1 = z4, eA2 = z4, eB0 = z4, eB1 = z4, eB2 = z4;
    float4 oA0 = z4, oA1 = z4, oA2 = z4, oB0 = z4, oB1 = z4, oB2 = z4;

// Load row GY into slot P (halo guards are per-lane; masked lanes keep zeros).
#define PRE(P, GY)                                                        \
    {                                                                     \
        int gy2_ = (GY);                                                  \
        if (gy2_ >= 0 && gy2_ < IMG_H) {                                  \
            const float* rA_ = Ai + (size_t)gy2_ * IMG_W;                 \
            const float* rB_ = Bi + (size_t)gy2_ * IMG_W;                 \
            if (g >= 1) {                                                 \
                P##A0 = *(const float4*)(rA_ + 4 * (g - 1));              \
                P##B0 = *(const float4*)(rB_ + 4 * (g - 1));              \
            }                                                             \
            P##A1 = *(const float4*)(rA_ + 4 * g);                        \
            P##B1 = *(const float4*)(rB_ + 4 * g);                        \
            if (g <= NG - 2) {                                            \
                P##A2 = *(const float4*)(rA_ + 4 * (g + 1));              \
                P##B2 = *(const float4*)(rB_ + 4 * (g + 1));              \
            }                                                             \
        }                                                                 \
    }

// One horizontal tap-source j: contributes to cols c with k=j-c in [0,11).
// Per-c accumulation order is k-ascending when HJ(0..13) run in order ==
// bit-identical to the verified round-2 k-loop.
#define HJ(J)                                                             \
    {                                                                     \
        float t_ = fa[J] * fb[J];                                         \
        _Pragma("unroll")                                                 \
        for (int c_ = 0; c_ < 4; ++c_) {                                  \
            int k_ = (J) - c_;                                            \
            if (k_ >= 0 && k_ < KW) {                                     \
                hA[c_] += w[k_] * fa[J];                                  \
                hB[c_] += w[k_] * fb[J];                                  \
                hP[c_] += w[k_] * t_;                                     \
            }                                                             \
        }                                                                 \
    }

// Consume slot P as input row I (gy = ybase+I-RAD): h-conv + vertical scatter.
#define CONS(I, P)                                                        \
    {                                                                     \
        int gy_ = ybase + (I) - RAD;                                      \
        if (gy_ >= 0 && gy_ < IMG_H) {                                    \
            const float* rA_ = Ai + (size_t)gy_ * IMG_W;                  \
            const float* rB_ = Bi + (size_t)gy_ * IMG_W;                  \
            int cl_ = 4 * g - 5, cr_ = 4 * g + 8;                         \
            float ea0_ = (cl_ >= 0) ? rA_[cl_] : 0.f;                     \
            float eb0_ = (cl_ >= 0) ? rB_[cl_] : 0.f;                     \
            float ea1_ = (cr_ < IMG_W) ? rA_[cr_] : 0.f;                  \
            float eb1_ = (cr_ < IMG_W) ? rB_[cr_] : 0.f;                  \
            float fa[14] = {ea0_, P##A0.x, P##A0.y, P##A0.z, P##A0.w,     \
                            P##A1.x, P##A1.y, P##A1.z, P##A1.w,           \
                            P##A2.x, P##A2.y, P##A2.z, P##A2.w, ea1_};    \
            float fb[14] = {eb0_, P##B0.x, P##B0.y, P##B0.z, P##B0.w,     \
                            P##B1.x, P##B1.y, P##B1.z, P##B1.w,           \
                            P##B2.x, P##B2.y, P##B2.z, P##B2.w, eb1_};    \
            float hA[4] = {0.f, 0.f, 0.f, 0.f};                           \
            float hB[4] = {0.f, 0.f, 0.f, 0.f};                           \
            float hP[4] = {0.f, 0.f, 0.f, 0.f};                           \
            HJ(0) HJ(1) HJ(2) HJ(3) HJ(4) HJ(5) HJ(6)                     \
            HJ(7) HJ(8) HJ(9) HJ(10) HJ(11) HJ(12) HJ(13)                 \
            _Pragma("unroll")                                             \
            for (int o_ = 0; o_ < T; ++o_) {                              \
                int k_ = (I) - o_;                                        \
                if (k_ >= 0 && k_ < KW) {                                 \
                    float wk_ = w[k_];                                    \
                    accA[o_].x += wk_ * hA[0]; accA[o_].y += wk_ * hA[1]; \
                    accA[o_].z += wk_ * hA[2]; accA[o_].w += wk_ * hA[3]; \
                    accB[o_].x += wk_ * hB[0]; accB[o_].y += wk_ * hB[1]; \
                    accB[o_].z += wk_ * hB[2]; accB[o_].w += wk_ * hB[3]; \
                    accP[o_].x += wk_ * hP[0]; accP[o_].y += wk_ * hP[1]; \
                    accP[o_].z += wk_ * hP[2]; accP[o_].w += wk_ * hP[3]; \
                }                                                         \
            }                                                             \
        }                                                                 \
    }

// Step I: issue row I+1's loads into slot NP, then consume slot CP as row I.
#define STEP(I, CP, NP)                                                   \
    {                                                                     \
        if ((I) + 1 < NROWS) PRE(NP, ybase + (I) + 1 - RAD)               \
        CONS(I, CP)                                                       \
    }

    // Prologue: row 0 into the even slot.
    PRE(e, ybase - RAD)

    STEP(0, e, o)
    STEP(1, o, e)
    STEP(2, e, o)
    STEP(3, o, e)
    STEP(4, e, o)
    STEP(5, o, e)
    STEP(6, e, o)
    STEP(7, o, e)
    STEP(8, e, o)
    STEP(9, o, e)
    STEP(10, e, o)
    STEP(11, o, e)
    STEP(12, e, o)
    STEP(13, o, e)

#undef STEP
#undef CONS
#undef HJ
#undef PRE

    // SSIM formula per pixel + per-thread accumulate (16 px/thread).
    float acc = 0.f;
#pragma unroll
    for (int o = 0; o < T; ++o) {
        acc += ssim_px(accA[o].x, accB[o].x, accP[o].x);
        acc += ssim_px(accA[o].y, accB[o].y, accP[o].y);
        acc += ssim_px(accA[o].z, accB[o].z, accP[o].z);
        acc += ssim_px(accA[o].w, accB[o].w, accP[o].w);
    }

    // Reduce: wave shuffle -> LDS -> one atomic per block.
#pragma unroll
    for (int off = 32; off > 0; off >>= 1)
        acc += __shfl_down(acc, off, 64);
    int wid = tid >> 6;
    int lane = tid & 63;
    if (lane == 0) wpart[wid] = acc;
    __syncthreads();
    if (tid == 0) {
        float s = (wpart[0] + wpart[1]) + (wpart[2] + wpart[3]);
        atomicAdd(out, s * inv_total);
    }
}

extern "C" void kernel_launch(void* const* d_in, const int* in_sizes, int n_in,
                              void* d_out, int out_size, void* d_ws, size_t ws_size,
                              hipStream_t stream) {
    const float* A = (const float*)d_in[0];
    const float* B = (const float*)d_in[1];
    float* out = (float*)d_out;

    const int total = in_sizes[0];                 // 32*1*512*512
    const int nimg = total / (IMG_H * IMG_W);      // 32

    hipMemsetAsync(d_out, 0, sizeof(float), stream);

    dim3 grid(IMG_H / (2 * T), nimg, 1);           // (64, 32)
    ssim_fused_kernel<<<grid, 256, 0, stream>>>(A, B, out, 1.0f / (float)total);
}

// Round 6
// 153.313 us; speedup vs baseline: 3.0098x; 1.1259x over previous
//
#include <hip/hip_runtime.h>
#include <math.h>

#define IMG_H 512
#define IMG_W 512
#define KW 11
#define RAD 5
#define T 4                     // output rows per block
#define NROWS (T + 2 * RAD)     // 14 input rows
#define LROW 548                // padded LDS row (floats); idx = col + 8

#define C1F (0.01f * 0.01f)
#define C2F (0.03f * 0.03f)

__device__ __forceinline__ float ssim_px(float mu1, float mu2, float sp) {
    float m12 = mu1 * mu2;
    float sigma = sp - m12;
    float sq = mu1 * mu1 + mu2 * mu2;
    return ((2.f * m12 + C1F) * (2.f * sigma + C2F)) / ((sq + C1F) * (sq + C2F));
}

// Design X (round 6): LDS row-staging.
//   Block: 256 threads x 2 cols = 512 cols, T=4 output rows. Grid (128, 32).
//   14 input rows staged once per block into double-buffered LDS (4-row
//   phases, 1 barrier per phase). Taps consumed from LDS via b64 reads at
//   8*tid + immediate offsets -> no per-iter address math, no per-lane halo
//   guards (edges are constant zeros written once).
// Allocator law (r0-r5): VGPR cap ~= 256/min_waves. (256,2)->128, fits the
//   ~100-reg dataflow honestly; (256,4)->64 would force spill. VGPR ~100 ->
//   4 waves/SIMD by HW; latency now hidden STRUCTURALLY (block pipeline),
//   not by wave count.
// r2 evidence: 8 waves + 64-reg squeeze = 48% busy with ~2x mov bloat.
// This trades wave count for a ~2x leaner instruction stream.
__global__ __launch_bounds__(256, 2)
void ssim_fused_kernel(const float* __restrict__ A, const float* __restrict__ B,
                       float* __restrict__ out, float inv_total) {
    __shared__ float sA[2][4][LROW];
    __shared__ float sB[2][4][LROW];
    __shared__ float wpart[4];

    const int tid = threadIdx.x;
    const int c0 = 2 * tid;              // first of this thread's 2 cols
    const int img = blockIdx.y;
    const int ybase = blockIdx.x * T;    // first output row of the block

    // Gaussian weights (sigma=1.5, K=11) — fp32 recipe matching np bit-exactly.
    float w[KW];
    {
        float s = 0.f;
#pragma unroll
        for (int i = 0; i < KW; ++i) {
            float d = (float)(i - RAD);
            w[i] = expf(-(d * d) / 4.5f);
            s += w[i];
        }
        float inv = 1.0f / s;
#pragma unroll
        for (int i = 0; i < KW; ++i) {
            w[i] *= inv;
            w[i] = __int_as_float(__builtin_amdgcn_readfirstlane(__float_as_int(w[i])));
        }
    }

    const float* __restrict__ Ai = A + (size_t)img * IMG_H * IMG_W;
    const float* __restrict__ Bi = B + (size_t)img * IMG_H * IMG_W;

    // Accumulators: 3 arrays x 2 cols x 4 rows = 24 floats.
    float aA0[T], aA1[T], aB0[T], aB1[T], aP0[T], aP1[T];
#pragma unroll
    for (int o = 0; o < T; ++o) {
        aA0[o] = 0.f; aA1[o] = 0.f;
        aB0[o] = 0.f; aB1[o] = 0.f;
        aP0[o] = 0.f; aP1[o] = 0.f;
    }

    // Edge zeros, written ONCE for both buffers & all slots:
    // idx 0..7   = cols -8..-1   (left zero padding)
    // idx 520..527 = cols 512..519 (right zero padding; taps reach idx 525)
    if (tid < 8) {
#pragma unroll
        for (int b = 0; b < 2; ++b)
#pragma unroll
            for (int s = 0; s < 4; ++s) {
                sA[b][s][tid] = 0.f;       sB[b][s][tid] = 0.f;
                sA[b][s][520 + tid] = 0.f; sB[b][s][520 + tid] = 0.f;
            }
    }

    float2 rgA[4], rgB[4];   // reg-staged next-phase rows (static idx only)

// Load phase P's rows (NS of them) into rg. gy bound check is wave-uniform;
// OOB rows stage zeros == the vertical zero-padding.
#define LOADPH(P, NS)                                                     \
    {                                                                     \
        _Pragma("unroll")                                                 \
        for (int s_ = 0; s_ < (NS); ++s_) {                               \
            int gy_ = ybase - RAD + 4 * (P) + s_;                         \
            float2 a_ = make_float2(0.f, 0.f);                            \
            float2 b_ = make_float2(0.f, 0.f);                            \
            if (gy_ >= 0 && gy_ < IMG_H) {                                \
                a_ = *(const float2*)(Ai + (size_t)gy_ * IMG_W + c0);     \
                b_ = *(const float2*)(Bi + (size_t)gy_ * IMG_W + c0);     \
            }                                                             \
            rgA[s_] = a_; rgB[s_] = b_;                                   \
        }                                                                 \
    }

// Write rg into LDS buffer BUF (cols c0,c0+1 -> idx c0+8, 8B aligned).
#define WRITEPH(BUF, NS)                                                  \
    {                                                                     \
        _Pragma("unroll")                                                 \
        for (int s_ = 0; s_ < (NS); ++s_) {                               \
            *(float2*)&sA[BUF][s_][c0 + 8] = rgA[s_];                     \
            *(float2*)&sB[BUF][s_][c0 + 8] = rgB[s_];                     \
        }                                                                 \
    }

// Consume slot S of buffer BUF as input row I (I literal 0..13).
// Taps: cols c0-5..c0+6. fa[m] = col c0-6+m = LDS idx c0+2+m, m=0..13.
//   col0 tap k -> fa[k+1]; col1 tap k -> fa[k+2]. k ascending == reference.
#define CONSROW(BUF, S, I)                                                \
    {                                                                     \
        float2 qa[7], qb[7];                                              \
        _Pragma("unroll")                                                 \
        for (int j_ = 0; j_ < 7; ++j_) {                                  \
            qa[j_] = *(const float2*)&sA[BUF][S][c0 + 2 + 2 * j_];        \
            qb[j_] = *(const float2*)&sB[BUF][S][c0 + 2 + 2 * j_];        \
        }                                                                 \
        float fa[14] = {qa[0].x, qa[0].y, qa[1].x, qa[1].y, qa[2].x,      \
                        qa[2].y, qa[3].x, qa[3].y, qa[4].x, qa[4].y,      \
                        qa[5].x, qa[5].y, qa[6].x, qa[6].y};              \
        float fb[14] = {qb[0].x, qb[0].y, qb[1].x, qb[1].y, qb[2].x,      \
                        qb[2].y, qb[3].x, qb[3].y, qb[4].x, qb[4].y,      \
                        qb[5].x, qb[5].y, qb[6].x, qb[6].y};              \
        float p[14];                                                      \
        _Pragma("unroll")                                                 \
        for (int m_ = 1; m_ < 13; ++m_) p[m_] = fa[m_] * fb[m_];          \
        float h0A = 0.f, h1A = 0.f, h0B = 0.f, h1B = 0.f;                 \
        float h0P = 0.f, h1P = 0.f;                                       \
        _Pragma("unroll")                                                 \
        for (int k_ = 0; k_ < KW; ++k_) {                                 \
            float wk_ = w[k_];                                            \
            h0A += wk_ * fa[k_ + 1]; h1A += wk_ * fa[k_ + 2];             \
            h0B += wk_ * fb[k_ + 1]; h1B += wk_ * fb[k_ + 2];             \
            h0P += wk_ * p[k_ + 1];  h1P += wk_ * p[k_ + 2];              \
        }                                                                 \
        _Pragma("unroll")                                                 \
        for (int o_ = 0; o_ < T; ++o_) {                                  \
            int k_ = (I) - o_;                                            \
            if (k_ >= 0 && k_ < KW) {                                     \
                float wk_ = w[k_];                                        \
                aA0[o_] += wk_ * h0A; aA1[o_] += wk_ * h1A;               \
                aB0[o_] += wk_ * h0B; aB1[o_] += wk_ * h1B;               \
                aP0[o_] += wk_ * h0P; aP1[o_] += wk_ * h1P;               \
            }                                                             \
        }                                                                 \
    }

    // ---- Phase pipeline: 1 barrier per phase.
    // Phase p consumes buf[p&1]; phase p stages phase p+1 into buf[(p+1)&1].
    // Write-vs-read hazards are all separated by exactly one barrier.
    LOADPH(0, 4) WRITEPH(0, 4)
    __syncthreads();

    LOADPH(1, 4)                                   // rows 4..7 -> regs
    CONSROW(0, 0, 0) CONSROW(0, 1, 1) CONSROW(0, 2, 2) CONSROW(0, 3, 3)
    WRITEPH(1, 4)
    __syncthreads();

    LOADPH(2, 4)                                   // rows 8..11 -> regs
    CONSROW(1, 0, 4) CONSROW(1, 1, 5) CONSROW(1, 2, 6) CONSROW(1, 3, 7)
    WRITEPH(0, 4)
    __syncthreads();

    LOADPH(3, 2)                                   // rows 12..13 -> regs
    CONSROW(0, 0, 8) CONSROW(0, 1, 9) CONSROW(0, 2, 10) CONSROW(0, 3, 11)
    WRITEPH(1, 2)
    __syncthreads();

    CONSROW(1, 0, 12) CONSROW(1, 1, 13)

#undef CONSROW
#undef WRITEPH
#undef LOADPH

    // SSIM per pixel + per-thread accumulate (8 px/thread).
    float acc = 0.f;
#pragma unroll
    for (int o = 0; o < T; ++o) {
        acc += ssim_px(aA0[o], aB0[o], aP0[o]);
        acc += ssim_px(aA1[o], aB1[o], aP1[o]);
    }

    // Reduce: wave shuffle -> LDS -> one atomic per block.
#pragma unroll
    for (int off = 32; off > 0; off >>= 1)
        acc += __shfl_down(acc, off, 64);
    int wid = tid >> 6;
    int lane = tid & 63;
    if (lane == 0) wpart[wid] = acc;
    __syncthreads();
    if (tid == 0) {
        float s = (wpart[0] + wpart[1]) + (wpart[2] + wpart[3]);
        atomicAdd(out, s * inv_total);
    }
}

extern "C" void kernel_launch(void* const* d_in, const int* in_sizes, int n_in,
                              void* d_out, int out_size, void* d_ws, size_t ws_size,
                              hipStream_t stream) {
    const float* A = (const float*)d_in[0];
    const float* B = (const float*)d_in[1];
    float* out = (float*)d_out;

    const int total = in_sizes[0];                 // 32*1*512*512
    const int nimg = total / (IMG_H * IMG_W);      // 32

    hipMemsetAsync(d_out, 0, sizeof(float), stream);

    dim3 grid(IMG_H / T, nimg, 1);                 // (128, 32)
    ssim_fused_kernel<<<grid, 256, 0, stream>>>(A, B, out, 1.0f / (float)total);
}